// Round 3
// baseline (187.014 us; speedup 1.0000x reference)
//
#include <hip/hip_runtime.h>
#include <stdint.h>

#define B_SZ   2
#define T_SEQ  2048
#define WIDTH_ 1024
#define NH     16
#define HD     64
#define WIN    256
#define MROWS  (B_SZ * T_SEQ)   // 4096
#define NQKV   1152             // 1024 q + 64 k + 64 v

typedef __attribute__((ext_vector_type(4))) float f32x4;
typedef __attribute__((ext_vector_type(8))) short s16x8;

typedef __attribute__((address_space(1))) const void gas_void;
typedef __attribute__((address_space(3))) void las_void;

#define MFMA(a, b, c) __builtin_amdgcn_mfma_f32_16x16x32_bf16((a), (b), (c), 0, 0, 0)

__device__ __forceinline__ void gload_lds16(const void* g, void* l) {
  __builtin_amdgcn_global_load_lds((gas_void*)g, (las_void*)l, 16, 0, 0);
}

__device__ __forceinline__ ushort f2bf(float f) {
  union { float f; uint32_t u; } v; v.f = f;
  uint32_t u = v.u;
  return (ushort)((u + 0x7FFFu + ((u >> 16) & 1u)) >> 16);
}

// ---------------------------------------------------------------------------
// Prep: cast x -> bf16, build Wqkv = [Wq;Wk;Wv] bf16 (1152x1024), Wf bf16.
// Each thread converts 4 floats (float4 load, ushort4 store).
// ---------------------------------------------------------------------------
__global__ void prep_kernel(const float* __restrict__ x,
                            const float* __restrict__ Wq,
                            const float* __restrict__ Wk,
                            const float* __restrict__ Wv,
                            const float* __restrict__ Wf,
                            ushort* __restrict__ xb,
                            ushort* __restrict__ wqkv,
                            ushort* __restrict__ wfb) {
  const int XN = MROWS * WIDTH_ / 4;      // 1048576 quads
  const int WQ = NQKV * WIDTH_ / 4;       // 294912 quads
  const int WF = WIDTH_ * WIDTH_ / 4;     // 262144 quads
  int i = blockIdx.x * blockDim.x + threadIdx.x;
  float4 v;
  ushort* dst;
  if (i < XN) {
    v = ((const float4*)x)[i];
    dst = xb + i * 4;
  } else if (i < XN + WQ) {
    int j = i - XN;
    int row = (j * 4) >> 10;
    int col = (j * 4) & 1023;
    const float* src = (row < 1024) ? (Wq + row * 1024 + col)
                     : (row < 1088) ? (Wk + (row - 1024) * 1024 + col)
                                    : (Wv + (row - 1088) * 1024 + col);
    v = *(const float4*)src;
    dst = wqkv + j * 4;
  } else if (i < XN + WQ + WF) {
    int j = i - XN - WQ;
    v = ((const float4*)Wf)[j];
    dst = wfb + j * 4;
  } else {
    return;
  }
  ushort4 o;
  o.x = f2bf(v.x); o.y = f2bf(v.y); o.z = f2bf(v.z); o.w = f2bf(v.w);
  *(ushort4*)dst = o;
}

// ---------------------------------------------------------------------------
// GEMM: C[M x N] = A[M x K(row-major bf16)] * B^T, B given as [N x K] row-major
// bf16. 128x128 tile, BK=32, 4 waves each owning a 64x64 subtile (4x4 frags of
// 16x16x32 MFMA). Staging via global_load_lds width-16 (m97 structure).
// MODE 0: N=1152, epilogue routes bf16 to qb / kb / vb.
// MODE 1: N=1024, epilogue writes fp32 Cf = acc + bias[n].
// ---------------------------------------------------------------------------
template <int MODE>
__global__ __launch_bounds__(256) void gemm_kernel(
    const ushort* __restrict__ A, const ushort* __restrict__ B,
    ushort* __restrict__ qb, ushort* __restrict__ kb, ushort* __restrict__ vb,
    float* __restrict__ Cf, const float* __restrict__ bias) {
  const int K = 1024;
  const int w = threadIdx.x >> 6;
  const int lane = threadIdx.x & 63;
  const int g = lane >> 4;
  const int r16 = lane & 15;
  const int m0 = blockIdx.y * 128;
  const int n0 = blockIdx.x * 128;
  const int wm = (w >> 1) * 64;
  const int wn = (w & 1) * 64;

  __shared__ ushort As[128 * 32];
  __shared__ ushort Bs[128 * 32];

  f32x4 acc[4][4] = {};

  for (int k0 = 0; k0 < K; k0 += 32) {
    // stage A and B tiles: 8 KiB each = 512 16B chunks; 256 threads x 2 iters
#pragma unroll
    for (int i = 0; i < 2; ++i) {
      int c = i * 256 + w * 64 + lane;          // chunk id 0..511
      int row = c >> 2;
      int ke = (c & 3) * 8;
      int ldsbase = (i * 256 + w * 64) * 16;    // wave-uniform byte base
      gload_lds16(A + (size_t)(m0 + row) * K + k0 + ke, (char*)As + ldsbase);
      gload_lds16(B + (size_t)(n0 + row) * K + k0 + ke, (char*)Bs + ldsbase);
    }
    __syncthreads();

    s16x8 af[4], bfr[4];
#pragma unroll
    for (int t = 0; t < 4; ++t) {
      af[t]  = *(const s16x8*)&As[(wm + t * 16 + r16) * 32 + g * 8];
      bfr[t] = *(const s16x8*)&Bs[(wn + t * 16 + r16) * 32 + g * 8];
    }
#pragma unroll
    for (int mb = 0; mb < 4; ++mb)
#pragma unroll
      for (int nb = 0; nb < 4; ++nb)
        acc[mb][nb] = MFMA(af[mb], bfr[nb], acc[mb][nb]);
    __syncthreads();
  }

  // epilogue: C/D layout col = r16, row = 4*g + r
#pragma unroll
  for (int mb = 0; mb < 4; ++mb)
#pragma unroll
    for (int nb = 0; nb < 4; ++nb) {
      int n = n0 + wn + nb * 16 + r16;
      int mbase = m0 + wm + mb * 16 + 4 * g;
      if (MODE == 0) {
#pragma unroll
        for (int r = 0; r < 4; ++r) {
          ushort h = f2bf(acc[mb][nb][r]);
          int m = mbase + r;
          if (n < 1024)      qb[m * 1024 + n] = h;
          else if (n < 1088) kb[m * 64 + (n - 1024)] = h;
          else               vb[m * 64 + (n - 1088)] = h;
        }
      } else {
        float bv = bias[n];
#pragma unroll
        for (int r = 0; r < 4; ++r)
          Cf[(size_t)(mbase + r) * 1024 + n] = acc[mb][nb][r] + bv;
      }
    }
}

// ---------------------------------------------------------------------------
// V transpose: vb (b*t, 64) -> vt (b, 64, t). Output-coalesced scalar kernel.
// ---------------------------------------------------------------------------
__global__ void vtrans_kernel(const ushort* __restrict__ vb,
                              ushort* __restrict__ vt) {
  int o = blockIdx.x * blockDim.x + threadIdx.x;  // 262144
  int t = o & 2047;
  int d = (o >> 11) & 63;
  int b = o >> 17;
  vt[o] = vb[(size_t)(b * 2048 + t) * 64 + d];
}

// ---------------------------------------------------------------------------
// Sliding-window attention. One wave per (b, head, 16-query tile).
// Swapped QK^T: S^T = mfma(K, Q) so lane column = query index; softmax reduce
// is two shfl_xor; P feeds PV's B operand directly (split-half k-map used
// consistently for the V^T A operand). K/V read from global (L2-resident).
// ---------------------------------------------------------------------------
__global__ __launch_bounds__(64) void attn_kernel(
    const ushort* __restrict__ qb, const ushort* __restrict__ kb,
    const ushort* __restrict__ vt, ushort* __restrict__ ao) {
  const int lane = threadIdx.x;
  const int g = lane >> 4;
  const int r16 = lane & 15;
  const int blk = blockIdx.x;            // b*16*128 + h*128 + qt
  const int qt = blk & 127;
  const int h = (blk >> 7) & 15;
  const int b = blk >> 11;
  const int q0 = qt * 16;
  const int qp = q0 + r16;

  // Q fragments (B operand of S^T mfma): col = r16 = query, k = d
  const ushort* qrow = qb + (size_t)(b * 2048 + qp) * 1024 + h * 64;
  s16x8 qf0 = *(const s16x8*)(qrow + g * 8);
  s16x8 qf1 = *(const s16x8*)(qrow + 32 + g * 8);

  f32x4 oacc[4] = {};
  float mrun = -1e30f, ls = 0.f;

  int kt0 = q0 - WIN;
  if (kt0 < 0) kt0 = 0;
  kt0 &= ~31;

  for (int kt = kt0; kt <= q0; kt += 32) {
    // K fragments (A operand): row = key index
    int kr0 = kt + r16;
    int kr1 = kt + 16 + r16;
    if (kr1 > 2047) kr1 = 2047;          // clamp (masked anyway)
    const ushort* kp0 = kb + (size_t)(b * 2048 + kr0) * 64;
    const ushort* kp1 = kb + (size_t)(b * 2048 + kr1) * 64;
    s16x8 k00 = *(const s16x8*)(kp0 + g * 8);
    s16x8 k01 = *(const s16x8*)(kp0 + 32 + g * 8);
    s16x8 k10 = *(const s16x8*)(kp1 + g * 8);
    s16x8 k11 = *(const s16x8*)(kp1 + 32 + g * 8);

    f32x4 s0 = {}, s1 = {};
    s0 = MFMA(k00, qf0, s0);
    s0 = MFMA(k01, qf1, s0);
    s1 = MFMA(k10, qf0, s1);
    s1 = MFMA(k11, qf1, s1);

    // mask + scale; S^T row = key = kt + 4g + r (+16), col = query = r16
    float p0[4], p1[4];
    float tm = -1e30f;
#pragma unroll
    for (int r = 0; r < 4; ++r) {
      int ka = kt + 4 * g + r;
      int kb2 = ka + 16;
      float v0 = (ka <= qp && qp - ka <= WIN) ? s0[r] * 0.125f : -1e30f;
      float v1 = (kb2 <= qp && qp - kb2 <= WIN) ? s1[r] * 0.125f : -1e30f;
      p0[r] = v0; p1[r] = v1;
      tm = fmaxf(tm, fmaxf(v0, v1));
    }
    tm = fmaxf(tm, __shfl_xor(tm, 16));
    tm = fmaxf(tm, __shfl_xor(tm, 32));

    float mnew = fmaxf(mrun, tm);
    float corr = __expf(mrun - mnew);
    float ts = 0.f;
    s16x8 pf;
#pragma unroll
    for (int r = 0; r < 4; ++r) {
      float e0 = __expf(p0[r] - mnew);
      float e1 = __expf(p1[r] - mnew);
      ts += e0 + e1;
      pf[r] = (short)f2bf(e0);
      pf[4 + r] = (short)f2bf(e1);
    }
    ts += __shfl_xor(ts, 16);
    ts += __shfl_xor(ts, 32);
    ls = ls * corr + ts;
    mrun = mnew;

#pragma unroll
    for (int db = 0; db < 4; ++db) oacc[db] *= corr;

    // PV: out^T[d][q] += V^T frag (A) x P frag (B), split-half k-map
#pragma unroll
    for (int db = 0; db < 4; ++db) {
      const ushort* vrow = vt + (size_t)(b * 64 + db * 16 + r16) * 2048 + kt;
      ushort4 va = *(const ushort4*)(vrow + 4 * g);
      ushort4 vc = *(const ushort4*)(vrow + 16 + 4 * g);
      s16x8 vf;
      vf[0] = (short)va.x; vf[1] = (short)va.y; vf[2] = (short)va.z; vf[3] = (short)va.w;
      vf[4] = (short)vc.x; vf[5] = (short)vc.y; vf[6] = (short)vc.z; vf[7] = (short)vc.w;
      oacc[db] = MFMA(vf, pf, oacc[db]);
    }
  }

  float inv = 1.0f / ls;
  ushort* orow = ao + (size_t)(b * 2048 + qp) * 1024 + h * 64;
#pragma unroll
  for (int db = 0; db < 4; ++db) {
    ushort4 o;
    o.x = f2bf(oacc[db][0] * inv);
    o.y = f2bf(oacc[db][1] * inv);
    o.z = f2bf(oacc[db][2] * inv);
    o.w = f2bf(oacc[db][3] * inv);
    *(ushort4*)(orow + db * 16 + 4 * g) = o;
  }
}

// ---------------------------------------------------------------------------
extern "C" void kernel_launch(void* const* d_in, const int* in_sizes, int n_in,
                              void* d_out, int out_size, void* d_ws, size_t ws_size,
                              hipStream_t stream) {
  const float* x  = (const float*)d_in[0];
  // d_in[1] = segment_pos (unused; reference masks with arange)
  const float* Wq = (const float*)d_in[2];
  const float* Wk = (const float*)d_in[3];
  const float* Wv = (const float*)d_in[4];
  const float* Wf = (const float*)d_in[5];
  const float* bf = (const float*)d_in[6];
  float* out = (float*)d_out;

  uint8_t* w8 = (uint8_t*)d_ws;
  ushort* xb   = (ushort*)(w8 + 0);          //  8 MiB  x bf16 (4096x1024)
  ushort* qbuf = (ushort*)(w8 + 8388608);    //  8 MiB  q bf16
  ushort* attn = (ushort*)(w8 + 16777216);   //  8 MiB  attn out bf16
  ushort* wqkv = (ushort*)(w8 + 25165824);   //  2.25 MiB (1152x1024)
  ushort* wfb  = (ushort*)(w8 + 27525120);   //  2 MiB
  // vt placed BEFORE kbuf/vbuf: attention's masked tail V-reads (up to 30 B
  // past vt's end for the last row) land in kbuf, which is valid memory.
  ushort* vt   = (ushort*)(w8 + 29622272);   //  512 KiB (b, 64, 2048)
  ushort* kbuf = (ushort*)(w8 + 30146560);   //  512 KiB (4096x64)
  ushort* vbuf = (ushort*)(w8 + 30670848);   //  512 KiB

  prep_kernel<<<6272, 256, 0, stream>>>(x, Wq, Wk, Wv, Wf, xb, wqkv, wfb);
  gemm_kernel<0><<<dim3(9, 32), 256, 0, stream>>>(xb, wqkv, qbuf, kbuf, vbuf,
                                                  nullptr, nullptr);
  vtrans_kernel<<<1024, 256, 0, stream>>>(vbuf, vt);
  attn_kernel<<<4096, 64, 0, stream>>>(qbuf, kbuf, vt, attn);
  gemm_kernel<1><<<dim3(8, 32), 256, 0, stream>>>(attn, wfb, nullptr, nullptr,
                                                  nullptr, out, bf);
}

// Round 4
// 158.598 us; speedup vs baseline: 1.1792x; 1.1792x over previous
//
#include <hip/hip_runtime.h>
#include <stdint.h>

#define B_SZ   2
#define T_SEQ  2048
#define WIDTH_ 1024
#define NH     16
#define HD     64
#define WIN    256
#define MROWS  (B_SZ * T_SEQ)   // 4096
#define NQKV   1152             // 1024 q + 64 k + 64 v

typedef __attribute__((ext_vector_type(4))) float f32x4;
typedef __attribute__((ext_vector_type(8))) short s16x8;

typedef __attribute__((address_space(1))) const void gas_void;
typedef __attribute__((address_space(3))) void las_void;

#define MFMA(a, b, c) __builtin_amdgcn_mfma_f32_16x16x32_bf16((a), (b), (c), 0, 0, 0)

__device__ __forceinline__ void gload_lds16(const void* g, void* l) {
  __builtin_amdgcn_global_load_lds((gas_void*)g, (las_void*)l, 16, 0, 0);
}

__device__ __forceinline__ ushort f2bf(float f) {
  union { float f; uint32_t u; } v; v.f = f;
  uint32_t u = v.u;
  return (ushort)((u + 0x7FFFu + ((u >> 16) & 1u)) >> 16);
}

// ---------------------------------------------------------------------------
// Prep: cast x -> bf16, build Wqkv = [Wq;Wk;Wv] bf16 (1152x1024), Wf bf16.
// ---------------------------------------------------------------------------
__global__ void prep_kernel(const float* __restrict__ x,
                            const float* __restrict__ Wq,
                            const float* __restrict__ Wk,
                            const float* __restrict__ Wv,
                            const float* __restrict__ Wf,
                            ushort* __restrict__ xb,
                            ushort* __restrict__ wqkv,
                            ushort* __restrict__ wfb) {
  const int XN = MROWS * WIDTH_ / 4;      // 1048576 quads
  const int WQ = NQKV * WIDTH_ / 4;       // 294912 quads
  const int WF = WIDTH_ * WIDTH_ / 4;     // 262144 quads
  int i = blockIdx.x * blockDim.x + threadIdx.x;
  float4 v;
  ushort* dst;
  if (i < XN) {
    v = ((const float4*)x)[i];
    dst = xb + i * 4;
  } else if (i < XN + WQ) {
    int j = i - XN;
    int row = (j * 4) >> 10;
    int col = (j * 4) & 1023;
    const float* src = (row < 1024) ? (Wq + row * 1024 + col)
                     : (row < 1088) ? (Wk + (row - 1024) * 1024 + col)
                                    : (Wv + (row - 1088) * 1024 + col);
    v = *(const float4*)src;
    dst = wqkv + j * 4;
  } else if (i < XN + WQ + WF) {
    int j = i - XN - WQ;
    v = ((const float4*)Wf)[j];
    dst = wfb + j * 4;
  } else {
    return;
  }
  ushort4 o;
  o.x = f2bf(v.x); o.y = f2bf(v.y); o.z = f2bf(v.z); o.w = f2bf(v.w);
  *(ushort4*)dst = o;
}

// ---------------------------------------------------------------------------
// GEMM: C[M x N] = A * B^T, A [M x 1024] bf16 row-major, B [N x 1024] bf16
// row-major. 128x128 tile, BK=32, 4 waves x 64x64 subtile. Double-buffered
// LDS (static unroll-by-2 so buffer choice is compile-time): stage(next) is
// issued right after the barrier, compute(cur) overlaps the loads, and the
// next barrier's vmcnt(0) drain lands a full compute phase after issue.
// MODE 0: N=1152, epilogue routes bf16 to qb / kb / vt (v transposed inline).
// MODE 1: N=1024, epilogue writes fp32 Cf = acc + bias[n].
// ---------------------------------------------------------------------------
#define G_STAGE(AS, BS, KOFF) do {                                          \
  _Pragma("unroll")                                                         \
  for (int i_ = 0; i_ < 2; ++i_) {                                          \
    int c_ = i_ * 256 + w * 64 + lane;                                      \
    int row_ = c_ >> 2;                                                     \
    int ke_ = (c_ & 3) * 8;                                                 \
    int ldsb_ = (i_ * 256 + w * 64) * 16;                                   \
    gload_lds16(A + (size_t)(m0 + row_) * 1024 + (KOFF) + ke_,              \
                (char*)(AS) + ldsb_);                                       \
    gload_lds16(B + (size_t)(n0 + row_) * 1024 + (KOFF) + ke_,              \
                (char*)(BS) + ldsb_);                                       \
  }                                                                         \
} while (0)

#define G_COMPUTE(AS, BS) do {                                              \
  s16x8 af_[4], bf_[4];                                                     \
  _Pragma("unroll")                                                         \
  for (int t_ = 0; t_ < 4; ++t_) {                                          \
    af_[t_] = *(const s16x8*)&(AS)[(wm + t_ * 16 + r16) * 32 + g * 8];      \
    bf_[t_] = *(const s16x8*)&(BS)[(wn + t_ * 16 + r16) * 32 + g * 8];      \
  }                                                                         \
  _Pragma("unroll")                                                         \
  for (int mb_ = 0; mb_ < 4; ++mb_)                                         \
    _Pragma("unroll")                                                       \
    for (int nb_ = 0; nb_ < 4; ++nb_)                                       \
      acc[mb_][nb_] = MFMA(af_[mb_], bf_[nb_], acc[mb_][nb_]);              \
} while (0)

template <int MODE>
__global__ __launch_bounds__(256) void gemm_kernel(
    const ushort* __restrict__ A, const ushort* __restrict__ B,
    ushort* __restrict__ qb, ushort* __restrict__ kb, ushort* __restrict__ vt,
    float* __restrict__ Cf, const float* __restrict__ bias) {
  const int w = threadIdx.x >> 6;
  const int lane = threadIdx.x & 63;
  const int g = lane >> 4;
  const int r16 = lane & 15;
  const int m0 = blockIdx.y * 128;
  const int n0 = blockIdx.x * 128;
  const int wm = (w >> 1) * 64;
  const int wn = (w & 1) * 64;

  __shared__ ushort As0[128 * 32];
  __shared__ ushort Bs0[128 * 32];
  __shared__ ushort As1[128 * 32];
  __shared__ ushort Bs1[128 * 32];

  f32x4 acc[4][4] = {};

  G_STAGE(As0, Bs0, 0);
  for (int k0 = 0; k0 < 1024; k0 += 64) {
    __syncthreads();                       // drains As0/Bs0 loads
    G_STAGE(As1, Bs1, k0 + 32);            // k0+32 <= 992, always valid
    G_COMPUTE(As0, Bs0);
    __syncthreads();                       // drains As1/Bs1 loads
    if (k0 + 64 < 1024) G_STAGE(As0, Bs0, k0 + 64);
    G_COMPUTE(As1, Bs1);
  }

  // epilogue: C/D layout col = r16, row = 4*g + r
#pragma unroll
  for (int mb = 0; mb < 4; ++mb)
#pragma unroll
    for (int nb = 0; nb < 4; ++nb) {
      int n = n0 + wn + nb * 16 + r16;
      int mbase = m0 + wm + mb * 16 + 4 * g;
      if (MODE == 0) {
#pragma unroll
        for (int r = 0; r < 4; ++r) {
          ushort h = f2bf(acc[mb][nb][r]);
          int m = mbase + r;
          if (n < 1024)      qb[m * 1024 + n] = h;
          else if (n < 1088) kb[m * 64 + (n - 1024)] = h;
          else               vt[((size_t)((m >> 11) * 64 + (n - 1088))) * 2048 +
                                (m & 2047)] = h;   // V transposed inline
        }
      } else {
        float bv = bias[n];
#pragma unroll
        for (int r = 0; r < 4; ++r)
          Cf[(size_t)(mbase + r) * 1024 + n] = acc[mb][nb][r] + bv;
      }
    }
}

// ---------------------------------------------------------------------------
// Sliding-window attention. One wave per (b, head, 32-query tile): two
// 16-query subtiles share K and V fragments (2x MFMA per byte loaded vs r3).
// Swapped QK^T: S^T = mfma(K, Q), lane column = query; softmax reduce is two
// shfl_xor; P feeds PV's B operand directly. Next k-tile's K fragments are
// prefetched before the softmax/PV phase to hide L2 latency.
// ---------------------------------------------------------------------------
__global__ __launch_bounds__(64) void attn_kernel(
    const ushort* __restrict__ qb, const ushort* __restrict__ kb,
    const ushort* __restrict__ vt, ushort* __restrict__ ao) {
  const int lane = threadIdx.x;
  const int g = lane >> 4;
  const int r16 = lane & 15;
  const int blk = blockIdx.x;            // b*16*64 + h*64 + qt
  const int qt = blk & 63;
  const int h = (blk >> 6) & 15;
  const int b = blk >> 10;
  const int q0 = qt * 32;
  const int qpA = q0 + r16;
  const int qpB = q0 + 16 + r16;

  // Q fragments (B operand): col = r16 = query, k = d
  const ushort* qrowA = qb + (size_t)(b * 2048 + qpA) * 1024 + h * 64;
  const ushort* qrowB = qb + (size_t)(b * 2048 + qpB) * 1024 + h * 64;
  s16x8 qfA0 = *(const s16x8*)(qrowA + g * 8);
  s16x8 qfA1 = *(const s16x8*)(qrowA + 32 + g * 8);
  s16x8 qfB0 = *(const s16x8*)(qrowB + g * 8);
  s16x8 qfB1 = *(const s16x8*)(qrowB + 32 + g * 8);

  f32x4 oaccA[4] = {}, oaccB[4] = {};
  float mA = -1e30f, lA = 0.f, mB = -1e30f, lB = 0.f;

  int kt0 = q0 - WIN;
  if (kt0 < 0) kt0 = 0;
  kt0 &= ~31;

  // prefetch K fragments for the first tile
  s16x8 k00, k01, k10, k11;
  {
    const ushort* kp0 = kb + (size_t)(b * 2048 + kt0 + r16) * 64;
    const ushort* kp1 = kb + (size_t)(b * 2048 + kt0 + 16 + r16) * 64;
    k00 = *(const s16x8*)(kp0 + g * 8);
    k01 = *(const s16x8*)(kp0 + 32 + g * 8);
    k10 = *(const s16x8*)(kp1 + g * 8);
    k11 = *(const s16x8*)(kp1 + 32 + g * 8);
  }

  for (int kt = kt0; kt <= q0; kt += 32) {
    s16x8 c00 = k00, c01 = k01, c10 = k10, c11 = k11;
    if (kt + 32 <= q0) {                 // prefetch next tile's K
      const ushort* kp0 = kb + (size_t)(b * 2048 + kt + 32 + r16) * 64;
      const ushort* kp1 = kb + (size_t)(b * 2048 + kt + 48 + r16) * 64;
      k00 = *(const s16x8*)(kp0 + g * 8);
      k01 = *(const s16x8*)(kp0 + 32 + g * 8);
      k10 = *(const s16x8*)(kp1 + g * 8);
      k11 = *(const s16x8*)(kp1 + 32 + g * 8);
    }

    f32x4 sA0 = {}, sA1 = {}, sB0 = {}, sB1 = {};
    sA0 = MFMA(c00, qfA0, sA0); sA0 = MFMA(c01, qfA1, sA0);
    sA1 = MFMA(c10, qfA0, sA1); sA1 = MFMA(c11, qfA1, sA1);
    sB0 = MFMA(c00, qfB0, sB0); sB0 = MFMA(c01, qfB1, sB0);
    sB1 = MFMA(c10, qfB0, sB1); sB1 = MFMA(c11, qfB1, sB1);

    // mask + scale; S^T row = key = kt + 4g + r (+16), col = query
    float pA0[4], pA1[4], pB0[4], pB1[4];
    float tmA = -1e30f, tmB = -1e30f;
#pragma unroll
    for (int r = 0; r < 4; ++r) {
      int ka = kt + 4 * g + r;
      int kc = ka + 16;
      float a0 = (ka <= qpA && qpA - ka <= WIN) ? sA0[r] * 0.125f : -1e30f;
      float a1 = (kc <= qpA && qpA - kc <= WIN) ? sA1[r] * 0.125f : -1e30f;
      float b0 = (ka <= qpB && qpB - ka <= WIN) ? sB0[r] * 0.125f : -1e30f;
      float b1 = (kc <= qpB && qpB - kc <= WIN) ? sB1[r] * 0.125f : -1e30f;
      pA0[r] = a0; pA1[r] = a1; pB0[r] = b0; pB1[r] = b1;
      tmA = fmaxf(tmA, fmaxf(a0, a1));
      tmB = fmaxf(tmB, fmaxf(b0, b1));
    }
    tmA = fmaxf(tmA, __shfl_xor(tmA, 16));
    tmA = fmaxf(tmA, __shfl_xor(tmA, 32));
    tmB = fmaxf(tmB, __shfl_xor(tmB, 16));
    tmB = fmaxf(tmB, __shfl_xor(tmB, 32));

    float mnA = fmaxf(mA, tmA), mnB = fmaxf(mB, tmB);
    float corrA = __expf(mA - mnA), corrB = __expf(mB - mnB);
    float tsA = 0.f, tsB = 0.f;
    s16x8 pfA, pfB;
#pragma unroll
    for (int r = 0; r < 4; ++r) {
      float eA0 = __expf(pA0[r] - mnA);
      float eA1 = __expf(pA1[r] - mnA);
      float eB0 = __expf(pB0[r] - mnB);
      float eB1 = __expf(pB1[r] - mnB);
      tsA += eA0 + eA1; tsB += eB0 + eB1;
      pfA[r] = (short)f2bf(eA0); pfA[4 + r] = (short)f2bf(eA1);
      pfB[r] = (short)f2bf(eB0); pfB[4 + r] = (short)f2bf(eB1);
    }
    tsA += __shfl_xor(tsA, 16); tsA += __shfl_xor(tsA, 32);
    tsB += __shfl_xor(tsB, 16); tsB += __shfl_xor(tsB, 32);
    lA = lA * corrA + tsA; mA = mnA;
    lB = lB * corrB + tsB; mB = mnB;

#pragma unroll
    for (int db = 0; db < 4; ++db) { oaccA[db] *= corrA; oaccB[db] *= corrB; }

    // PV: out^T[d][q] += V^T frag (A, shared) x P frag (B), split-half k-map
#pragma unroll
    for (int db = 0; db < 4; ++db) {
      const ushort* vrow = vt + (size_t)(b * 64 + db * 16 + r16) * 2048 + kt;
      ushort4 va = *(const ushort4*)(vrow + 4 * g);
      ushort4 vc = *(const ushort4*)(vrow + 16 + 4 * g);
      s16x8 vf;
      vf[0] = (short)va.x; vf[1] = (short)va.y; vf[2] = (short)va.z; vf[3] = (short)va.w;
      vf[4] = (short)vc.x; vf[5] = (short)vc.y; vf[6] = (short)vc.z; vf[7] = (short)vc.w;
      oaccA[db] = MFMA(vf, pfA, oaccA[db]);
      oaccB[db] = MFMA(vf, pfB, oaccB[db]);
    }
  }

  float invA = 1.0f / lA, invB = 1.0f / lB;
  ushort* orowA = ao + (size_t)(b * 2048 + qpA) * 1024 + h * 64;
  ushort* orowB = ao + (size_t)(b * 2048 + qpB) * 1024 + h * 64;
#pragma unroll
  for (int db = 0; db < 4; ++db) {
    ushort4 oA, oB;
    oA.x = f2bf(oaccA[db][0] * invA); oA.y = f2bf(oaccA[db][1] * invA);
    oA.z = f2bf(oaccA[db][2] * invA); oA.w = f2bf(oaccA[db][3] * invA);
    oB.x = f2bf(oaccB[db][0] * invB); oB.y = f2bf(oaccB[db][1] * invB);
    oB.z = f2bf(oaccB[db][2] * invB); oB.w = f2bf(oaccB[db][3] * invB);
    *(ushort4*)(orowA + db * 16 + 4 * g) = oA;
    *(ushort4*)(orowB + db * 16 + 4 * g) = oB;
  }
}

// ---------------------------------------------------------------------------
extern "C" void kernel_launch(void* const* d_in, const int* in_sizes, int n_in,
                              void* d_out, int out_size, void* d_ws, size_t ws_size,
                              hipStream_t stream) {
  const float* x  = (const float*)d_in[0];
  // d_in[1] = segment_pos (unused; reference masks with arange)
  const float* Wq = (const float*)d_in[2];
  const float* Wk = (const float*)d_in[3];
  const float* Wv = (const float*)d_in[4];
  const float* Wf = (const float*)d_in[5];
  const float* bf = (const float*)d_in[6];
  float* out = (float*)d_out;

  uint8_t* w8 = (uint8_t*)d_ws;
  ushort* xb   = (ushort*)(w8 + 0);          //  8 MiB  x bf16 (4096x1024)
  ushort* qbuf = (ushort*)(w8 + 8388608);    //  8 MiB  q bf16
  ushort* attn = (ushort*)(w8 + 16777216);   //  8 MiB  attn out bf16
  ushort* wqkv = (ushort*)(w8 + 25165824);   //  2.25 MiB (1152x1024)
  ushort* wfb  = (ushort*)(w8 + 27525120);   //  2 MiB
  ushort* kbuf = (ushort*)(w8 + 29622272);   //  512 KiB (4096x64)
  ushort* vt   = (ushort*)(w8 + 30146560);   //  512 KiB (b, 64, 2048)

  prep_kernel<<<6272, 256, 0, stream>>>(x, Wq, Wk, Wv, Wf, xb, wqkv, wfb);
  gemm_kernel<0><<<dim3(9, 32), 256, 0, stream>>>(xb, wqkv, qbuf, kbuf, vt,
                                                  nullptr, nullptr);
  attn_kernel<<<2048, 64, 0, stream>>>(qbuf, kbuf, vt, attn);
  gemm_kernel<1><<<dim3(8, 32), 256, 0, stream>>>(attn, wfb, nullptr, nullptr,
                                                  nullptr, out, bf);
}

// Round 7
// 153.886 us; speedup vs baseline: 1.2153x; 1.0306x over previous
//
#include <hip/hip_runtime.h>
#include <stdint.h>

#define B_SZ   2
#define T_SEQ  2048
#define WIDTH_ 1024
#define NH     16
#define HD     64
#define WIN    256
#define MROWS  (B_SZ * T_SEQ)   // 4096
#define NQKV   1152             // 1024 q + 64 k + 64 v

typedef __attribute__((ext_vector_type(4))) float f32x4;
typedef __attribute__((ext_vector_type(8))) short s16x8;

typedef __attribute__((address_space(1))) const void gas_void;
typedef __attribute__((address_space(3))) void las_void;

#define MFMA(a, b, c) __builtin_amdgcn_mfma_f32_16x16x32_bf16((a), (b), (c), 0, 0, 0)

// Explicit drain of in-flight global_load_lds. __syncthreads() alone is NOT
// guaranteed to emit s_waitcnt vmcnt(0) before s_barrier (m97 observed it,
// but r6's post-timing divergence at 4-8 blocks/CU says the drain is not on
// the race-critical path here). Belt-and-braces: ~free if redundant.
#define VMEM_DRAIN() asm volatile("s_waitcnt vmcnt(0)" ::: "memory")

__device__ __forceinline__ void gload_lds16(const void* g, void* l) {
  __builtin_amdgcn_global_load_lds((gas_void*)g, (las_void*)l, 16, 0, 0);
}

__device__ __forceinline__ ushort f2bf(float f) {
  union { float f; uint32_t u; } v; v.f = f;
  uint32_t u = v.u;
  return (ushort)((u + 0x7FFFu + ((u >> 16) & 1u)) >> 16);
}

// ---------------------------------------------------------------------------
// Prep: cast x -> bf16, build Wqkv = [Wq;Wk;Wv] bf16 (1152x1024), Wf bf16.
// ---------------------------------------------------------------------------
__global__ void prep_kernel(const float* __restrict__ x,
                            const float* __restrict__ Wq,
                            const float* __restrict__ Wk,
                            const float* __restrict__ Wv,
                            const float* __restrict__ Wf,
                            ushort* __restrict__ xb,
                            ushort* __restrict__ wqkv,
                            ushort* __restrict__ wfb) {
  const int XN = MROWS * WIDTH_ / 4;      // 1048576 quads
  const int WQ = NQKV * WIDTH_ / 4;       // 294912 quads
  const int WF = WIDTH_ * WIDTH_ / 4;     // 262144 quads
  int i = blockIdx.x * blockDim.x + threadIdx.x;
  float4 v;
  ushort* dst;
  if (i < XN) {
    v = ((const float4*)x)[i];
    dst = xb + i * 4;
  } else if (i < XN + WQ) {
    int j = i - XN;
    int row = (j * 4) >> 10;
    int col = (j * 4) & 1023;
    const float* src = (row < 1024) ? (Wq + row * 1024 + col)
                     : (row < 1088) ? (Wk + (row - 1024) * 1024 + col)
                                    : (Wv + (row - 1088) * 1024 + col);
    v = *(const float4*)src;
    dst = wqkv + j * 4;
  } else if (i < XN + WQ + WF) {
    int j = i - XN - WQ;
    v = ((const float4*)Wf)[j];
    dst = wfb + j * 4;
  } else {
    return;
  }
  ushort4 o;
  o.x = f2bf(v.x); o.y = f2bf(v.y); o.z = f2bf(v.z); o.w = f2bf(v.w);
  *(ushort4*)dst = o;
}

// ---------------------------------------------------------------------------
// GEMM: C[M x N] = A * B^T, A [M x 1024], B [N x 1024], both bf16 row-major.
// 64x64 tile (4+ blocks/CU), BK=32, double-buffered LDS with EXPLICIT
// vmcnt(0) drains before each barrier, 4 waves each owning a 32x32 subtile.
// Bijective XCD-chunk blockIdx swizzle.
// MODE 0: N=1152, epilogue routes bf16 to qb / kb / vt (v transposed inline).
// MODE 1: N=1024, epilogue writes fp32 Cf = acc + bias[n].
// ---------------------------------------------------------------------------
#define G_STAGE(AS, BS, KOFF) do {                                          \
  int c_ = w * 64 + lane;              /* 0..255 */                         \
  int row_ = c_ >> 2;                                                       \
  int ke_ = (c_ & 3) * 8;                                                   \
  int ldsb_ = c_ * 16;                 /* wave-uniform base + lane*16 */    \
  gload_lds16(A + (size_t)(m0 + row_) * 1024 + (KOFF) + ke_,                \
              (char*)(AS) + ldsb_);                                         \
  gload_lds16(B + (size_t)(n0 + row_) * 1024 + (KOFF) + ke_,                \
              (char*)(BS) + ldsb_);                                         \
} while (0)

#define G_COMPUTE(AS, BS) do {                                              \
  s16x8 af_[2], bf_[2];                                                     \
  _Pragma("unroll")                                                         \
  for (int t_ = 0; t_ < 2; ++t_) {                                          \
    af_[t_] = *(const s16x8*)&(AS)[(wm + t_ * 16 + r16) * 32 + g * 8];      \
    bf_[t_] = *(const s16x8*)&(BS)[(wn + t_ * 16 + r16) * 32 + g * 8];      \
  }                                                                         \
  _Pragma("unroll")                                                         \
  for (int mb_ = 0; mb_ < 2; ++mb_)                                         \
    _Pragma("unroll")                                                       \
    for (int nb_ = 0; nb_ < 2; ++nb_)                                       \
      acc[mb_][nb_] = MFMA(af_[mb_], bf_[nb_], acc[mb_][nb_]);              \
} while (0)

template <int MODE>
__global__ __launch_bounds__(256) void gemm_kernel(
    const ushort* __restrict__ A, const ushort* __restrict__ B,
    ushort* __restrict__ qb, ushort* __restrict__ kb, ushort* __restrict__ vt,
    float* __restrict__ Cf, const float* __restrict__ bias) {
  const int NBX = (MODE == 0) ? 18 : 16;
  const int nwg = NBX * 64;              // 1152 / 1024, both % 8 == 0
  const int cpx = nwg >> 3;
  int swz = (blockIdx.x & 7) * cpx + (blockIdx.x >> 3);
  const int bx = swz % NBX;
  const int by = swz / NBX;

  const int w = threadIdx.x >> 6;
  const int lane = threadIdx.x & 63;
  const int g = lane >> 4;
  const int r16 = lane & 15;
  const int m0 = by * 64;
  const int n0 = bx * 64;
  const int wm = (w >> 1) * 32;
  const int wn = (w & 1) * 32;

  __shared__ ushort As0[64 * 32];
  __shared__ ushort Bs0[64 * 32];
  __shared__ ushort As1[64 * 32];
  __shared__ ushort Bs1[64 * 32];

  f32x4 acc[2][2] = {};

  G_STAGE(As0, Bs0, 0);
  for (int k0 = 0; k0 < 1024; k0 += 64) {
    VMEM_DRAIN();                          // As0/Bs0 loads landed
    __syncthreads();
    G_STAGE(As1, Bs1, k0 + 32);            // k0+32 <= 992, always valid
    G_COMPUTE(As0, Bs0);
    VMEM_DRAIN();                          // As1/Bs1 loads landed
    __syncthreads();
    if (k0 + 64 < 1024) G_STAGE(As0, Bs0, k0 + 64);
    G_COMPUTE(As1, Bs1);
  }

  // epilogue: C/D layout col = r16, row = 4*g + r
#pragma unroll
  for (int mb = 0; mb < 2; ++mb)
#pragma unroll
    for (int nb = 0; nb < 2; ++nb) {
      int n = n0 + wn + nb * 16 + r16;
      int mbase = m0 + wm + mb * 16 + 4 * g;
      if (MODE == 0) {
#pragma unroll
        for (int r = 0; r < 4; ++r) {
          ushort h = f2bf(acc[mb][nb][r]);
          int m = mbase + r;
          if (n < 1024)      qb[m * 1024 + n] = h;
          else if (n < 1088) kb[m * 64 + (n - 1024)] = h;
          else               vt[((size_t)((m >> 11) * 64 + (n - 1088))) * 2048 +
                                (m & 2047)] = h;   // V transposed inline
        }
      } else {
        float bv = bias[n];
#pragma unroll
        for (int r = 0; r < 4; ++r)
          Cf[(size_t)(mbase + r) * 1024 + n] = acc[mb][nb][r] + bv;
      }
    }
}

// ---------------------------------------------------------------------------
// Sliding-window attention. One wave per (b, head, 32-query tile): two
// 16-query subtiles share K and V fragments. Swapped QK^T: S^T = mfma(K, Q),
// lane column = query. V fragments for the CURRENT tile are loaded before the
// QK/softmax phase (L2 latency hides under the exp chain); next tile's K is
// prefetched likewise. s_setprio(1) wraps the MFMA clusters (T5).
// All K/V/Q reads verified in-bounds (max row index 2047 per batch).
// ---------------------------------------------------------------------------
__global__ __launch_bounds__(64) void attn_kernel(
    const ushort* __restrict__ qb, const ushort* __restrict__ kb,
    const ushort* __restrict__ vt, ushort* __restrict__ ao) {
  const int lane = threadIdx.x;
  const int g = lane >> 4;
  const int r16 = lane & 15;
  const int blk = blockIdx.x;            // b*1024 + h*64 + qt
  const int qt = blk & 63;
  const int h = (blk >> 6) & 15;
  const int b = blk >> 10;
  const int q0 = qt * 32;
  const int qpA = q0 + r16;
  const int qpB = q0 + 16 + r16;

  // Q fragments (B operand): col = r16 = query, k = d
  const ushort* qrowA = qb + (size_t)(b * 2048 + qpA) * 1024 + h * 64;
  const ushort* qrowB = qb + (size_t)(b * 2048 + qpB) * 1024 + h * 64;
  s16x8 qfA0 = *(const s16x8*)(qrowA + g * 8);
  s16x8 qfA1 = *(const s16x8*)(qrowA + 32 + g * 8);
  s16x8 qfB0 = *(const s16x8*)(qrowB + g * 8);
  s16x8 qfB1 = *(const s16x8*)(qrowB + 32 + g * 8);

  f32x4 oaccA[4] = {}, oaccB[4] = {};
  float mA = -1e30f, lA = 0.f, mB = -1e30f, lB = 0.f;

  int kt0 = q0 - WIN;
  if (kt0 < 0) kt0 = 0;
  kt0 &= ~31;

  // prefetch K fragments for the first tile
  s16x8 k00, k01, k10, k11;
  {
    const ushort* kp0 = kb + (size_t)(b * 2048 + kt0 + r16) * 64;
    const ushort* kp1 = kb + (size_t)(b * 2048 + kt0 + 16 + r16) * 64;
    k00 = *(const s16x8*)(kp0 + g * 8);
    k01 = *(const s16x8*)(kp0 + 32 + g * 8);
    k10 = *(const s16x8*)(kp1 + g * 8);
    k11 = *(const s16x8*)(kp1 + 32 + g * 8);
  }

  for (int kt = kt0; kt <= q0; kt += 32) {
    s16x8 c00 = k00, c01 = k01, c10 = k10, c11 = k11;

    // V fragments for CURRENT tile, loaded before the softmax chain
    s16x8 vfr[4];
#pragma unroll
    for (int db = 0; db < 4; ++db) {
      const ushort* vrow = vt + (size_t)(b * 64 + db * 16 + r16) * 2048 + kt;
      uint2 va = *(const uint2*)(vrow + 4 * g);
      uint2 vc = *(const uint2*)(vrow + 16 + 4 * g);
      union { s16x8 v; uint32_t d[4]; } u;
      u.d[0] = va.x; u.d[1] = va.y; u.d[2] = vc.x; u.d[3] = vc.y;
      vfr[db] = u.v;
    }

    if (kt + 32 <= q0) {                 // prefetch next tile's K
      const ushort* kp0 = kb + (size_t)(b * 2048 + kt + 32 + r16) * 64;
      const ushort* kp1 = kb + (size_t)(b * 2048 + kt + 48 + r16) * 64;
      k00 = *(const s16x8*)(kp0 + g * 8);
      k01 = *(const s16x8*)(kp0 + 32 + g * 8);
      k10 = *(const s16x8*)(kp1 + g * 8);
      k11 = *(const s16x8*)(kp1 + 32 + g * 8);
    }

    f32x4 sA0 = {}, sA1 = {}, sB0 = {}, sB1 = {};
    __builtin_amdgcn_s_setprio(1);
    sA0 = MFMA(c00, qfA0, sA0); sA0 = MFMA(c01, qfA1, sA0);
    sA1 = MFMA(c10, qfA0, sA1); sA1 = MFMA(c11, qfA1, sA1);
    sB0 = MFMA(c00, qfB0, sB0); sB0 = MFMA(c01, qfB1, sB0);
    sB1 = MFMA(c10, qfB0, sB1); sB1 = MFMA(c11, qfB1, sB1);
    __builtin_amdgcn_s_setprio(0);

    // mask + scale; S^T row = key = kt + 4g + r (+16), col = query
    float pA0[4], pA1[4], pB0[4], pB1[4];
    float tmA = -1e30f, tmB = -1e30f;
#pragma unroll
    for (int r = 0; r < 4; ++r) {
      int ka = kt + 4 * g + r;
      int kc = ka + 16;
      float a0 = (ka <= qpA && qpA - ka <= WIN) ? sA0[r] * 0.125f : -1e30f;
      float a1 = (kc <= qpA && qpA - kc <= WIN) ? sA1[r] * 0.125f : -1e30f;
      float b0 = (ka <= qpB && qpB - ka <= WIN) ? sB0[r] * 0.125f : -1e30f;
      float b1 = (kc <= qpB && qpB - kc <= WIN) ? sB1[r] * 0.125f : -1e30f;
      pA0[r] = a0; pA1[r] = a1; pB0[r] = b0; pB1[r] = b1;
      tmA = fmaxf(tmA, fmaxf(a0, a1));
      tmB = fmaxf(tmB, fmaxf(b0, b1));
    }
    tmA = fmaxf(tmA, __shfl_xor(tmA, 16));
    tmA = fmaxf(tmA, __shfl_xor(tmA, 32));
    tmB = fmaxf(tmB, __shfl_xor(tmB, 16));
    tmB = fmaxf(tmB, __shfl_xor(tmB, 32));

    float mnA = fmaxf(mA, tmA), mnB = fmaxf(mB, tmB);
    float corrA = __expf(mA - mnA), corrB = __expf(mB - mnB);
    float tsA = 0.f, tsB = 0.f;
    s16x8 pfA, pfB;
#pragma unroll
    for (int r = 0; r < 4; ++r) {
      float eA0 = __expf(pA0[r] - mnA);
      float eA1 = __expf(pA1[r] - mnA);
      float eB0 = __expf(pB0[r] - mnB);
      float eB1 = __expf(pB1[r] - mnB);
      tsA += eA0 + eA1; tsB += eB0 + eB1;
      pfA[r] = (short)f2bf(eA0); pfA[4 + r] = (short)f2bf(eA1);
      pfB[r] = (short)f2bf(eB0); pfB[4 + r] = (short)f2bf(eB1);
    }
    tsA += __shfl_xor(tsA, 16); tsA += __shfl_xor(tsA, 32);
    tsB += __shfl_xor(tsB, 16); tsB += __shfl_xor(tsB, 32);
    lA = lA * corrA + tsA; mA = mnA;
    lB = lB * corrB + tsB; mB = mnB;

#pragma unroll
    for (int db = 0; db < 4; ++db) { oaccA[db] *= corrA; oaccB[db] *= corrB; }

    // PV: out^T[d][q] += V^T frag (A, shared) x P frag (B), split-half k-map
    __builtin_amdgcn_s_setprio(1);
#pragma unroll
    for (int db = 0; db < 4; ++db) {
      oaccA[db] = MFMA(vfr[db], pfA, oaccA[db]);
      oaccB[db] = MFMA(vfr[db], pfB, oaccB[db]);
    }
    __builtin_amdgcn_s_setprio(0);
  }

  float invA = 1.0f / lA, invB = 1.0f / lB;
  ushort* orowA = ao + (size_t)(b * 2048 + qpA) * 1024 + h * 64;
  ushort* orowB = ao + (size_t)(b * 2048 + qpB) * 1024 + h * 64;
#pragma unroll
  for (int db = 0; db < 4; ++db) {
    ushort4 oA, oB;
    oA.x = f2bf(oaccA[db][0] * invA); oA.y = f2bf(oaccA[db][1] * invA);
    oA.z = f2bf(oaccA[db][2] * invA); oA.w = f2bf(oaccA[db][3] * invA);
    oB.x = f2bf(oaccB[db][0] * invB); oB.y = f2bf(oaccB[db][1] * invB);
    oB.z = f2bf(oaccB[db][2] * invB); oB.w = f2bf(oaccB[db][3] * invB);
    *(ushort4*)(orowA + db * 16 + 4 * g) = oA;
    *(ushort4*)(orowB + db * 16 + 4 * g) = oB;
  }
}

// ---------------------------------------------------------------------------
extern "C" void kernel_launch(void* const* d_in, const int* in_sizes, int n_in,
                              void* d_out, int out_size, void* d_ws, size_t ws_size,
                              hipStream_t stream) {
  const float* x  = (const float*)d_in[0];
  // d_in[1] = segment_pos (unused; reference masks with arange)
  const float* Wq = (const float*)d_in[2];
  const float* Wk = (const float*)d_in[3];
  const float* Wv = (const float*)d_in[4];
  const float* Wf = (const float*)d_in[5];
  const float* bf = (const float*)d_in[6];
  float* out = (float*)d_out;

  uint8_t* w8 = (uint8_t*)d_ws;
  ushort* xb   = (ushort*)(w8 + 0);          //  8 MiB  x bf16 (4096x1024)
  ushort* qbuf = (ushort*)(w8 + 8388608);    //  8 MiB  q bf16
  ushort* attn = (ushort*)(w8 + 16777216);   //  8 MiB  attn out bf16
  ushort* wqkv = (ushort*)(w8 + 25165824);   //  2.25 MiB (1152x1024)
  ushort* wfb  = (ushort*)(w8 + 27525120);   //  2 MiB
  ushort* kbuf = (ushort*)(w8 + 29622272);   //  512 KiB (4096x64)
  ushort* vt   = (ushort*)(w8 + 30146560);   //  512 KiB (b, 64, 2048)

  prep_kernel<<<6272, 256, 0, stream>>>(x, Wq, Wk, Wv, Wf, xb, wqkv, wfb);
  gemm_kernel<0><<<1152, 256, 0, stream>>>(xb, wqkv, qbuf, kbuf, vt,
                                           nullptr, nullptr);
  attn_kernel<<<2048, 64, 0, stream>>>(qbuf, kbuf, vt, attn);
  gemm_kernel<1><<<1024, 256, 0, stream>>>(attn, wfb, nullptr, nullptr,
                                           nullptr, out, bf);
}

// Round 8
// 152.866 us; speedup vs baseline: 1.2234x; 1.0067x over previous
//
#include <hip/hip_runtime.h>
#include <stdint.h>

#define B_SZ   2
#define T_SEQ  2048
#define WIDTH_ 1024
#define NH     16
#define HD     64
#define WIN    256
#define MROWS  (B_SZ * T_SEQ)   // 4096
#define NQKV   1152             // 1024 q + 64 k + 64 v

typedef __attribute__((ext_vector_type(4))) float f32x4;
typedef __attribute__((ext_vector_type(8))) short s16x8;

typedef __attribute__((address_space(1))) const void gas_void;
typedef __attribute__((address_space(3))) void las_void;

#define MFMA(a, b, c) __builtin_amdgcn_mfma_f32_16x16x32_bf16((a), (b), (c), 0, 0, 0)

// Counted waits: never drain to 0 in the steady-state loop (T4); the just-
// issued next-next-tile loads stay in flight across the barrier.
#define VM_WAIT4() asm volatile("s_waitcnt vmcnt(4)" ::: "memory")
#define VM_WAIT0() asm volatile("s_waitcnt vmcnt(0)" ::: "memory")

__device__ __forceinline__ void gload_lds16(const void* g, void* l) {
  __builtin_amdgcn_global_load_lds((gas_void*)g, (las_void*)l, 16, 0, 0);
}

__device__ __forceinline__ ushort f2bf(float f) {
  union { float f; uint32_t u; } v; v.f = f;
  uint32_t u = v.u;
  return (ushort)((u + 0x7FFFu + ((u >> 16) & 1u)) >> 16);
}

// ---------------------------------------------------------------------------
// Prep: cast x -> bf16, build Wqkv = [Wq;Wk;Wv] bf16 (1152x1024), Wf bf16.
// ---------------------------------------------------------------------------
__global__ void prep_kernel(const float* __restrict__ x,
                            const float* __restrict__ Wq,
                            const float* __restrict__ Wk,
                            const float* __restrict__ Wv,
                            const float* __restrict__ Wf,
                            ushort* __restrict__ xb,
                            ushort* __restrict__ wqkv,
                            ushort* __restrict__ wfb) {
  const int XN = MROWS * WIDTH_ / 4;      // 1048576 quads
  const int WQ = NQKV * WIDTH_ / 4;       // 294912 quads
  const int WF = WIDTH_ * WIDTH_ / 4;     // 262144 quads
  int i = blockIdx.x * blockDim.x + threadIdx.x;
  float4 v;
  ushort* dst;
  if (i < XN) {
    v = ((const float4*)x)[i];
    dst = xb + i * 4;
  } else if (i < XN + WQ) {
    int j = i - XN;
    int row = (j * 4) >> 10;
    int col = (j * 4) & 1023;
    const float* src = (row < 1024) ? (Wq + row * 1024 + col)
                     : (row < 1088) ? (Wk + (row - 1024) * 1024 + col)
                                    : (Wv + (row - 1088) * 1024 + col);
    v = *(const float4*)src;
    dst = wqkv + j * 4;
  } else if (i < XN + WQ + WF) {
    int j = i - XN - WQ;
    v = ((const float4*)Wf)[j];
    dst = wfb + j * 4;
  } else {
    return;
  }
  ushort4 o;
  o.x = f2bf(v.x); o.y = f2bf(v.y); o.z = f2bf(v.z); o.w = f2bf(v.w);
  *(ushort4*)dst = o;
}

// ---------------------------------------------------------------------------
// GEMM: C[M x N] = A * B^T, A [M x 1024], B [N x 1024], both bf16 row-major.
// 64x64 tile, BK=64, 2-deep counted-vmcnt pipeline (T3/T4 minimal form):
//   prologue: STAGE(buf0,k=0), STAGE(buf1,k=64)           -> 8 loads in flight
//   iter(buf,k): vmcnt(4) [oldest 4 = this buf's loads done; 4 newer fly]
//                -> barrier -> compute(buf) -> barrier -> STAGE(buf, k+128)
//   final iter (k=960) has no newer loads in flight -> vmcnt(0).
// LDS rows are 128 B -> 16-way read conflict; fixed per rule #21: linear LDS
// dest + inverse-swizzled GLOBAL source (ke ^ (row&7)<<3) + same XOR on read.
// MODE 0: N=1152, epilogue routes bf16 to qb / kb / vt (v transposed inline).
// MODE 1: N=1024, epilogue writes fp32 Cf = acc + bias[n].
// ---------------------------------------------------------------------------
#define G_STAGE64(AS, BS, KOFF) do {                                        \
  _Pragma("unroll")                                                         \
  for (int i_ = 0; i_ < 2; ++i_) {                                          \
    int c_ = i_ * 256 + w * 64 + lane;      /* 0..511 */                    \
    int row_ = c_ >> 3;                     /* 8 x 16B chunks per row */    \
    int ke_ = ((c_ & 7) * 8) ^ ((row_ & 7) << 3);   /* swizzled source */   \
    int ldsb_ = (i_ * 256 + w * 64) * 16;   /* wave-uniform base */         \
    gload_lds16(A + (size_t)(m0 + row_) * 1024 + (KOFF) + ke_,              \
                (char*)(AS) + ldsb_);                                       \
    gload_lds16(B + (size_t)(n0 + row_) * 1024 + (KOFF) + ke_,              \
                (char*)(BS) + ldsb_);                                       \
  }                                                                         \
} while (0)

#define G_COMPUTE64(AS, BS) do {                                            \
  _Pragma("unroll")                                                         \
  for (int ks_ = 0; ks_ < 2; ++ks_) {                                       \
    s16x8 af_[2], bf_[2];                                                   \
    _Pragma("unroll")                                                       \
    for (int t_ = 0; t_ < 2; ++t_) {                                        \
      int ra_ = wm + t_ * 16 + r16;                                         \
      int rb_ = wn + t_ * 16 + r16;                                         \
      af_[t_] = *(const s16x8*)&(AS)[ra_ * 64 +                             \
                  ((ks_ * 32 + g * 8) ^ ((ra_ & 7) << 3))];                 \
      bf_[t_] = *(const s16x8*)&(BS)[rb_ * 64 +                             \
                  ((ks_ * 32 + g * 8) ^ ((rb_ & 7) << 3))];                 \
    }                                                                       \
    _Pragma("unroll")                                                       \
    for (int mb_ = 0; mb_ < 2; ++mb_)                                       \
      _Pragma("unroll")                                                     \
      for (int nb_ = 0; nb_ < 2; ++nb_)                                     \
        acc[mb_][nb_] = MFMA(af_[mb_], bf_[nb_], acc[mb_][nb_]);            \
  }                                                                         \
} while (0)

#define G_ITER(AS, BS, K)  do {                                             \
  if ((K) == 960) { VM_WAIT0(); } else { VM_WAIT4(); }                      \
  __syncthreads();                                                          \
  G_COMPUTE64(AS, BS);                                                      \
  __syncthreads();                                                          \
  if ((K) + 128 < 1024) G_STAGE64(AS, BS, (K) + 128);                       \
} while (0)

template <int MODE>
__global__ __launch_bounds__(256) void gemm_kernel(
    const ushort* __restrict__ A, const ushort* __restrict__ B,
    ushort* __restrict__ qb, ushort* __restrict__ kb, ushort* __restrict__ vt,
    float* __restrict__ Cf, const float* __restrict__ bias) {
  const int NBX = (MODE == 0) ? 18 : 16;
  const int nwg = NBX * 64;              // 1152 / 1024, both % 8 == 0
  const int cpx = nwg >> 3;
  int swz = (blockIdx.x & 7) * cpx + (blockIdx.x >> 3);
  const int bx = swz % NBX;
  const int by = swz / NBX;

  const int w = threadIdx.x >> 6;
  const int lane = threadIdx.x & 63;
  const int g = lane >> 4;
  const int r16 = lane & 15;
  const int m0 = by * 64;
  const int n0 = bx * 64;
  const int wm = (w >> 1) * 32;
  const int wn = (w & 1) * 32;

  __shared__ ushort As0[64 * 64];
  __shared__ ushort Bs0[64 * 64];
  __shared__ ushort As1[64 * 64];
  __shared__ ushort Bs1[64 * 64];

  f32x4 acc[2][2] = {};

  G_STAGE64(As0, Bs0, 0);
  G_STAGE64(As1, Bs1, 64);
#pragma unroll
  for (int k0 = 0; k0 < 1024; k0 += 128) {
    G_ITER(As0, Bs0, k0);
    G_ITER(As1, Bs1, k0 + 64);
  }

  // epilogue: C/D layout col = r16, row = 4*g + r
#pragma unroll
  for (int mb = 0; mb < 2; ++mb)
#pragma unroll
    for (int nb = 0; nb < 2; ++nb) {
      int n = n0 + wn + nb * 16 + r16;
      int mbase = m0 + wm + mb * 16 + 4 * g;
      if (MODE == 0) {
#pragma unroll
        for (int r = 0; r < 4; ++r) {
          ushort h = f2bf(acc[mb][nb][r]);
          int m = mbase + r;
          if (n < 1024)      qb[m * 1024 + n] = h;
          else if (n < 1088) kb[m * 64 + (n - 1024)] = h;
          else               vt[((size_t)((m >> 11) * 64 + (n - 1088))) * 2048 +
                                (m & 2047)] = h;   // V transposed inline
        }
      } else {
        float bv = bias[n];
#pragma unroll
        for (int r = 0; r < 4; ++r)
          Cf[(size_t)(mbase + r) * 1024 + n] = acc[mb][nb][r] + bv;
      }
    }
}

// ---------------------------------------------------------------------------
// Sliding-window attention, KVBLK=64. One wave per (b, head, 32-query tile).
// Per iteration: 4 key-16-subtiles (s=0..3), ONE softmax reduce + ONE online
// rescale per 64 keys, 2x the independent-chain ILP of the 32-key version
// (this kernel is latency-bound at 8 waves/CU; VGPR is free -> spend it).
// Swapped QK^T: S^T = mfma(K, Q), lane col = query. Masked tail reads land in
// valid ws (vt follows kbuf). launch_bounds(64,2) caps VGPR at 256.
// ---------------------------------------------------------------------------
__global__ __launch_bounds__(64, 2) void attn_kernel(
    const ushort* __restrict__ qb, const ushort* __restrict__ kb,
    const ushort* __restrict__ vt, ushort* __restrict__ ao) {
  const int lane = threadIdx.x;
  const int g = lane >> 4;
  const int r16 = lane & 15;
  const int blk = blockIdx.x;            // b*1024 + h*64 + qt
  const int qt = blk & 63;
  const int h = (blk >> 6) & 15;
  const int b = blk >> 10;
  const int q0 = qt * 32;
  const int qpA = q0 + r16;
  const int qpB = q0 + 16 + r16;

  // Q fragments (B operand): col = r16 = query, k = d
  const ushort* qrowA = qb + (size_t)(b * 2048 + qpA) * 1024 + h * 64;
  const ushort* qrowB = qb + (size_t)(b * 2048 + qpB) * 1024 + h * 64;
  s16x8 qfA0 = *(const s16x8*)(qrowA + g * 8);
  s16x8 qfA1 = *(const s16x8*)(qrowA + 32 + g * 8);
  s16x8 qfB0 = *(const s16x8*)(qrowB + g * 8);
  s16x8 qfB1 = *(const s16x8*)(qrowB + 32 + g * 8);

  f32x4 oaccA[4] = {}, oaccB[4] = {};
  float mA = -1e30f, lA = 0.f, mB = -1e30f, lB = 0.f;

  int kt0 = q0 - WIN;
  if (kt0 < 0) kt0 = 0;
  kt0 &= ~31;

  // prefetch K fragments for the first 64-key block (subtiles s=0..3)
  s16x8 pk[4][2];
#pragma unroll
  for (int s = 0; s < 4; ++s) {
    const ushort* kp = kb + (size_t)(b * 2048 + kt0 + s * 16 + r16) * 64;
    pk[s][0] = *(const s16x8*)(kp + g * 8);
    pk[s][1] = *(const s16x8*)(kp + 32 + g * 8);
  }

  for (int kt = kt0; kt <= q0; kt += 64) {
    s16x8 c[4][2];
#pragma unroll
    for (int s = 0; s < 4; ++s) { c[s][0] = pk[s][0]; c[s][1] = pk[s][1]; }

    // V fragments for CURRENT 64-key block (keys kt..kt+63), before softmax
    s16x8 vfr[4][2];
#pragma unroll
    for (int db = 0; db < 4; ++db) {
      const ushort* vrow = vt + (size_t)(b * 64 + db * 16 + r16) * 2048 + kt;
      uint2 va0 = *(const uint2*)(vrow + 4 * g);
      uint2 va1 = *(const uint2*)(vrow + 16 + 4 * g);
      uint2 vb0 = *(const uint2*)(vrow + 32 + 4 * g);
      uint2 vb1 = *(const uint2*)(vrow + 48 + 4 * g);
      union { s16x8 v; uint32_t d[4]; } u0, u1;
      u0.d[0] = va0.x; u0.d[1] = va0.y; u0.d[2] = va1.x; u0.d[3] = va1.y;
      u1.d[0] = vb0.x; u1.d[1] = vb0.y; u1.d[2] = vb1.x; u1.d[3] = vb1.y;
      vfr[db][0] = u0.v; vfr[db][1] = u1.v;
    }

    if (kt + 64 <= q0) {                 // prefetch next 64-key block's K
#pragma unroll
      for (int s = 0; s < 4; ++s) {
        const ushort* kp = kb + (size_t)(b * 2048 + kt + 64 + s * 16 + r16) * 64;
        pk[s][0] = *(const s16x8*)(kp + g * 8);
        pk[s][1] = *(const s16x8*)(kp + 32 + g * 8);
      }
    }

    // QK^T: 16 MFMA (4 subtiles x 2 d-halves x 2 query-sets)
    f32x4 sA[4], sB[4];
    __builtin_amdgcn_s_setprio(1);
#pragma unroll
    for (int s = 0; s < 4; ++s) {
      f32x4 z = {};
      sA[s] = MFMA(c[s][0], qfA0, z); sA[s] = MFMA(c[s][1], qfA1, sA[s]);
      sB[s] = MFMA(c[s][0], qfB0, z); sB[s] = MFMA(c[s][1], qfB1, sB[s]);
    }
    __builtin_amdgcn_s_setprio(0);

    // mask + scale; key for (s, g, r) = kt + s*16 + 4g + r; col = query
    float pA[4][4], pB[4][4];
    float tmA = -1e30f, tmB = -1e30f;
#pragma unroll
    for (int s = 0; s < 4; ++s)
#pragma unroll
      for (int r = 0; r < 4; ++r) {
        int ka = kt + s * 16 + 4 * g + r;
        float a = (ka <= qpA && qpA - ka <= WIN) ? sA[s][r] * 0.125f : -1e30f;
        float bv = (ka <= qpB && qpB - ka <= WIN) ? sB[s][r] * 0.125f : -1e30f;
        pA[s][r] = a; pB[s][r] = bv;
        tmA = fmaxf(tmA, a); tmB = fmaxf(tmB, bv);
      }
    tmA = fmaxf(tmA, __shfl_xor(tmA, 16));
    tmA = fmaxf(tmA, __shfl_xor(tmA, 32));
    tmB = fmaxf(tmB, __shfl_xor(tmB, 16));
    tmB = fmaxf(tmB, __shfl_xor(tmB, 32));

    float mnA = fmaxf(mA, tmA), mnB = fmaxf(mB, tmB);
    float corrA = __expf(mA - mnA), corrB = __expf(mB - mnB);
    float tsA = 0.f, tsB = 0.f;
    s16x8 pfA0, pfA1, pfB0, pfB1;
#pragma unroll
    for (int r = 0; r < 4; ++r) {
      float eA0 = __expf(pA[0][r] - mnA);
      float eA1 = __expf(pA[1][r] - mnA);
      float eA2 = __expf(pA[2][r] - mnA);
      float eA3 = __expf(pA[3][r] - mnA);
      float eB0 = __expf(pB[0][r] - mnB);
      float eB1 = __expf(pB[1][r] - mnB);
      float eB2 = __expf(pB[2][r] - mnB);
      float eB3 = __expf(pB[3][r] - mnB);
      tsA += (eA0 + eA1) + (eA2 + eA3);
      tsB += (eB0 + eB1) + (eB2 + eB3);
      pfA0[r] = (short)f2bf(eA0); pfA0[4 + r] = (short)f2bf(eA1);
      pfA1[r] = (short)f2bf(eA2); pfA1[4 + r] = (short)f2bf(eA3);
      pfB0[r] = (short)f2bf(eB0); pfB0[4 + r] = (short)f2bf(eB1);
      pfB1[r] = (short)f2bf(eB2); pfB1[4 + r] = (short)f2bf(eB3);
    }
    tsA += __shfl_xor(tsA, 16); tsA += __shfl_xor(tsA, 32);
    tsB += __shfl_xor(tsB, 16); tsB += __shfl_xor(tsB, 32);
    lA = lA * corrA + tsA; mA = mnA;
    lB = lB * corrB + tsB; mB = mnB;

#pragma unroll
    for (int db = 0; db < 4; ++db) { oaccA[db] *= corrA; oaccB[db] *= corrB; }

    // PV: out^T[d][q] += V^T frag (A, shared) x P frag (B); split-half k-map
    // consistent between pf packing and vfr packing for each 32-key half.
    __builtin_amdgcn_s_setprio(1);
#pragma unroll
    for (int db = 0; db < 4; ++db) {
      oaccA[db] = MFMA(vfr[db][0], pfA0, oaccA[db]);
      oaccA[db] = MFMA(vfr[db][1], pfA1, oaccA[db]);
      oaccB[db] = MFMA(vfr[db][0], pfB0, oaccB[db]);
      oaccB[db] = MFMA(vfr[db][1], pfB1, oaccB[db]);
    }
    __builtin_amdgcn_s_setprio(0);
  }

  float invA = 1.0f / lA, invB = 1.0f / lB;
  ushort* orowA = ao + (size_t)(b * 2048 + qpA) * 1024 + h * 64;
  ushort* orowB = ao + (size_t)(b * 2048 + qpB) * 1024 + h * 64;
#pragma unroll
  for (int db = 0; db < 4; ++db) {
    ushort4 oA, oB;
    oA.x = f2bf(oaccA[db][0] * invA); oA.y = f2bf(oaccA[db][1] * invA);
    oA.z = f2bf(oaccA[db][2] * invA); oA.w = f2bf(oaccA[db][3] * invA);
    oB.x = f2bf(oaccB[db][0] * invB); oB.y = f2bf(oaccB[db][1] * invB);
    oB.z = f2bf(oaccB[db][2] * invB); oB.w = f2bf(oaccB[db][3] * invB);
    *(ushort4*)(orowA + db * 16 + 4 * g) = oA;
    *(ushort4*)(orowB + db * 16 + 4 * g) = oB;
  }
}

// ---------------------------------------------------------------------------
extern "C" void kernel_launch(void* const* d_in, const int* in_sizes, int n_in,
                              void* d_out, int out_size, void* d_ws, size_t ws_size,
                              hipStream_t stream) {
  const float* x  = (const float*)d_in[0];
  // d_in[1] = segment_pos (unused; reference masks with arange)
  const float* Wq = (const float*)d_in[2];
  const float* Wk = (const float*)d_in[3];
  const float* Wv = (const float*)d_in[4];
  const float* Wf = (const float*)d_in[5];
  const float* bf = (const float*)d_in[6];
  float* out = (float*)d_out;

  uint8_t* w8 = (uint8_t*)d_ws;
  ushort* xb   = (ushort*)(w8 + 0);          //  8 MiB  x bf16 (4096x1024)
  ushort* qbuf = (ushort*)(w8 + 8388608);    //  8 MiB  q bf16
  ushort* attn = (ushort*)(w8 + 16777216);   //  8 MiB  attn out bf16
  ushort* wqkv = (ushort*)(w8 + 25165824);   //  2.25 MiB (1152x1024)
  ushort* wfb  = (ushort*)(w8 + 27525120);   //  2 MiB
  ushort* kbuf = (ushort*)(w8 + 29622272);   //  512 KiB (4096x64)
  ushort* vt   = (ushort*)(w8 + 30146560);   //  512 KiB (b, 64, 2048)

  prep_kernel<<<6272, 256, 0, stream>>>(x, Wq, Wk, Wv, Wf, xb, wqkv, wfb);
  gemm_kernel<0><<<1152, 256, 0, stream>>>(xb, wqkv, qbuf, kbuf, vt,
                                           nullptr, nullptr);
  attn_kernel<<<2048, 64, 0, stream>>>(qbuf, kbuf, vt, attn);
  gemm_kernel<1><<<1024, 256, 0, stream>>>(attn, wfb, nullptr, nullptr,
                                           nullptr, out, bf);
}